// Round 12
// baseline (393.047 us; speedup 1.0000x reference)
//
#include <hip/hip_runtime.h>
#include <hip/hip_bf16.h>
#include <math.h>

#define Bv 4
#define Sv 2048
#define Dv 1024
#define Hv 16
#define HD 64
#define NEGV (-1.0e9f)

typedef __attribute__((ext_vector_type(8))) short bf16x8;   // 8 bf16 = 16 B
typedef __attribute__((ext_vector_type(4))) short s16x4;    // 4 bf16 = 8 B
typedef __attribute__((ext_vector_type(4))) float f32x4;    // MFMA C/D

__device__ __forceinline__ short f2bf(float f) {
    union { __hip_bfloat16 h; short s; } u;
    u.h = __float2bfloat16(f);
    return u.s;
}

#if __has_builtin(__builtin_amdgcn_exp2f)
#define EXP2F(x) __builtin_amdgcn_exp2f(x)
#else
#define EXP2F(x) __expf((x) * 0.6931471805599453f)
#endif

__device__ __forceinline__ void glds16(const void* g, void* l) {
    __builtin_amdgcn_global_load_lds(
        (const __attribute__((address_space(1))) void*)g,
        (__attribute__((address_space(3))) void*)l, 16, 0, 0);
}

// ---------------------------------------------------------------------------
// fp32 -> bf16 bulk convert. 8 elems/thread. Single-tensor (fallback).
// ---------------------------------------------------------------------------
__global__ __launch_bounds__(256) void cvt_bf16(const float* __restrict__ X,
                                                unsigned short* __restrict__ Y) {
    const size_t i = ((size_t)blockIdx.x * 256 + threadIdx.x) * 8;
    const float4 a = *(const float4*)&X[i];
    const float4 b = *(const float4*)&X[i + 4];
    bf16x8 o = {f2bf(a.x), f2bf(a.y), f2bf(a.z), f2bf(a.w),
                f2bf(b.x), f2bf(b.y), f2bf(b.z), f2bf(b.w)};
    *(bf16x8*)&Y[i] = o;
}

// Multi-tensor cvt: blockIdx.y selects (x,y) pair. Grid (4096, nz).
__global__ __launch_bounds__(256) void cvt3(const float* __restrict__ x0,
                                            const float* __restrict__ x1,
                                            const float* __restrict__ x2,
                                            unsigned short* __restrict__ y0,
                                            unsigned short* __restrict__ y1,
                                            unsigned short* __restrict__ y2) {
    const int zz = blockIdx.y;
    const float* X = (zz == 0) ? x0 : (zz == 1) ? x1 : x2;
    unsigned short* Y = (zz == 0) ? y0 : (zz == 1) ? y1 : y2;
    const size_t i = ((size_t)blockIdx.x * 256 + threadIdx.x) * 8;
    const float4 a = *(const float4*)&X[i];
    const float4 b = *(const float4*)&X[i + 4];
    bf16x8 o = {f2bf(a.x), f2bf(a.y), f2bf(a.z), f2bf(a.w),
                f2bf(b.x), f2bf(b.y), f2bf(b.z), f2bf(b.w)};
    *(bf16x8*)&Y[i] = o;
}

// ---------------------------------------------------------------------------
// fp32 W [K=1024][N=1024] -> bf16 W^T [N][K]. Grid (16,16), 256 thr.
// ---------------------------------------------------------------------------
__device__ __forceinline__ void transpose_w_body(const float* __restrict__ W,
                                                 unsigned short* __restrict__ WT) {
    __shared__ float T[64][65];
    const int t = threadIdx.x;
    const int n0 = blockIdx.x * 64, k0 = blockIdx.y * 64;
    #pragma unroll
    for (int i = 0; i < 4; ++i) {
        const int k = (t >> 4) + 16 * i;
        const int nc = (t & 15) * 4;
        const float4 v = *(const float4*)&W[(size_t)(k0 + k) * 1024 + n0 + nc];
        T[k][nc + 0] = v.x; T[k][nc + 1] = v.y;
        T[k][nc + 2] = v.z; T[k][nc + 3] = v.w;
    }
    __syncthreads();
    const int n = t >> 2, kc = (t & 3) * 16;
    #pragma unroll
    for (int j4 = 0; j4 < 4; ++j4) {
        s16x4 o;
        #pragma unroll
        for (int jj = 0; jj < 4; ++jj) o[jj] = f2bf(T[kc + j4 * 4 + jj][n]);
        *(s16x4*)&WT[(size_t)(n0 + n) * 1024 + k0 + kc + j4 * 4] = o;
    }
}

__global__ __launch_bounds__(256) void transpose_w(const float* __restrict__ W,
                                                   unsigned short* __restrict__ WT) {
    transpose_w_body(W, WT);
}

// All 4 weight transposes in ONE launch. Grid (16,16,4); dst slot z.
__global__ __launch_bounds__(256) void transpose_w4(const float* __restrict__ W0,
                                                    const float* __restrict__ W1,
                                                    const float* __restrict__ W2,
                                                    const float* __restrict__ W3,
                                                    unsigned short* __restrict__ WTb) {
    const int z = blockIdx.z;
    const float* W = (z == 0) ? W0 : (z == 1) ? W1 : (z == 2) ? W2 : W3;
    transpose_w_body(W, WTb + (size_t)z * 1048576);
}

// ---------------------------------------------------------------------------
// bf16 V [BH][S][64] -> V^T [BH][64][S] (FALLBACK ONLY). Grid (S/64, nBH).
// ---------------------------------------------------------------------------
__global__ __launch_bounds__(256) void transpose_v(const unsigned short* __restrict__ Vin,
                                                   unsigned short* __restrict__ VT) {
    __shared__ unsigned short T[64][72];
    const int t = threadIdx.x;
    const int s0 = blockIdx.x * 64;
    const int bh = blockIdx.y;
    const size_t ib = (size_t)bh * Sv * 64;
    const size_t ob = (size_t)bh * 64 * Sv;
    {
        const int s = t >> 2, dc = (t & 3) * 16;
        const bf16x8 a = *(const bf16x8*)&Vin[ib + (size_t)(s0 + s) * 64 + dc];
        const bf16x8 b = *(const bf16x8*)&Vin[ib + (size_t)(s0 + s) * 64 + dc + 8];
        *(bf16x8*)&T[s][dc] = a;
        *(bf16x8*)&T[s][dc + 8] = b;
    }
    __syncthreads();
    const int dv = t >> 2, sc = (t & 3) * 16;
    #pragma unroll
    for (int j4 = 0; j4 < 4; ++j4) {
        s16x4 o;
        #pragma unroll
        for (int jj = 0; jj < 4; ++jj) o[jj] = (short)T[sc + j4 * 4 + jj][dv];
        *(s16x4*)&VT[ob + (size_t)dv * Sv + s0 + sc + j4 * 4] = o;
    }
}

// ---------------------------------------------------------------------------
// bf16 MFMA GEMM (FALLBACK): C = X(bf16) @ W + bias, W^T [N][K] bf16.
// ---------------------------------------------------------------------------
template <int PERM>
__global__ __launch_bounds__(256) void gemm_mfma(const unsigned short* __restrict__ X,
                                                 const unsigned short* __restrict__ WT,
                                                 const float* __restrict__ bias,
                                                 void* __restrict__ Cv,
                                                 int M, int N, int K) {
    __shared__ short As[128 * 32];
    __shared__ short Bs[128 * 32];

    const int t = threadIdx.x;
    const int lane = t & 63, w = t >> 6;
    const int l15 = lane & 15, quad = lane >> 4;
    const int m0 = blockIdx.y * 128, n0 = blockIdx.x * 128;
    const int wm = (w >> 1) * 64, wn = (w & 1) * 64;

    f32x4 acc[4][4];
    #pragma unroll
    for (int mi = 0; mi < 4; ++mi)
        #pragma unroll
        for (int ni = 0; ni < 4; ++ni) acc[mi][ni] = (f32x4){0.f, 0.f, 0.f, 0.f};

    const int srow = lane >> 2;
    const int skc = (lane & 3) * 8;

    for (int k0 = 0; k0 < K; k0 += 32) {
        #pragma unroll
        for (int i = 0; i < 2; ++i) {
            const int seg = w * 2 + i;
            const int row = seg * 16 + srow;
            glds16(&WT[(size_t)(n0 + row) * K + k0 + skc], &Bs[seg * 512]);
            glds16(&X[(size_t)(m0 + row) * K + k0 + skc], &As[seg * 512]);
        }
        __syncthreads();

        bf16x8 afr[4], bfr[4];
        #pragma unroll
        for (int mi = 0; mi < 4; ++mi)
            afr[mi] = *(const bf16x8*)&As[(wm + mi * 16 + l15) * 32 + quad * 8];
        #pragma unroll
        for (int ni = 0; ni < 4; ++ni)
            bfr[ni] = *(const bf16x8*)&Bs[(wn + ni * 16 + l15) * 32 + quad * 8];
        #pragma unroll
        for (int mi = 0; mi < 4; ++mi)
            #pragma unroll
            for (int ni = 0; ni < 4; ++ni)
                acc[mi][ni] = __builtin_amdgcn_mfma_f32_16x16x32_bf16(
                    afr[mi], bfr[ni], acc[mi][ni], 0, 0, 0);
        __syncthreads();
    }

    #pragma unroll
    for (int mi = 0; mi < 4; ++mi) {
        #pragma unroll
        for (int ni = 0; ni < 4; ++ni) {
            const int col = n0 + wn + ni * 16 + l15;
            const float bsv = bias[col];
            #pragma unroll
            for (int r = 0; r < 4; ++r) {
                const int row = m0 + wm + mi * 16 + quad * 4 + r;
                const float vv = acc[mi][ni][r] + bsv;
                if constexpr (PERM == 0) {
                    ((float*)Cv)[(size_t)row * N + col] = vv;
                } else {
                    const int bb = row / Sv, s = row % Sv;
                    const int hh = col >> 6, d = col & 63;
                    ((unsigned short*)Cv)[((((size_t)bb * Hv + hh) * Sv + s) << 6) + d] =
                        (unsigned short)f2bf(vv);
                }
            }
        }
    }
}

// ---------------------------------------------------------------------------
// QKV projection GEMM, 64Mx128N tile (R11 lesson: 128x128 at short K is
// co-residency-starved; 64-tile doubles grid to 3072 blocks = 12/CU).
// bf16 A via global_load_lds (m97 staging). 4 waves: wave w owns
// (wm=(w>>1)*32, wn=(w&1)*64), acc 2x4. Staging: 12 segs (4 A + 8 B),
// wave stages segs 3w..3w+2. Grid (8,128,nz) XCD-chunk-swizzled bijective.
// z per raw index via za/zb/zc: 0=Q,1=K,2=V. z==2 writes V^T [BH][64][S].
// NOTE: identifiers must avoid macros Bv/Sv/Dv/Hv/HD/NEGV.
// ---------------------------------------------------------------------------
__global__ __launch_bounds__(256) void gemm_qkv_b(const unsigned short* __restrict__ Xq,
                                                  const unsigned short* __restrict__ Xk,
                                                  const unsigned short* __restrict__ Xv,
                                                  const unsigned short* __restrict__ WTb,
                                                  const float* __restrict__ bq,
                                                  const float* __restrict__ bk,
                                                  const float* __restrict__ bv,
                                                  unsigned short* __restrict__ Oq,
                                                  unsigned short* __restrict__ Ok,
                                                  unsigned short* __restrict__ Ov,
                                                  int za, int zb, int zc) {
    __shared__ short As[64 * 32];
    __shared__ short Bs[128 * 32];

    const int nz = gridDim.z;
    const int hw = blockIdx.x + 8 * (blockIdx.y + 128 * blockIdx.z);
    const int cpx = 128 * nz;                      // nwg/8
    const int wl = (hw & 7) * cpx + (hw >> 3);     // bijective chunk swizzle
    const int bx = wl & 7, by = (wl >> 3) & 127, bzr = wl >> 10;
    const int z = (bzr == 0) ? za : (bzr == 1) ? zb : zc;

    const unsigned short* X = (z == 0) ? Xq : (z == 1) ? Xk : Xv;
    const unsigned short* WT = WTb + (size_t)z * 1048576;
    const float* bias = (z == 0) ? bq : (z == 1) ? bk : bv;

    const int t = threadIdx.x;
    const int lane = t & 63, w = t >> 6;
    const int l15 = lane & 15, quad = lane >> 4;
    const int m0 = by * 64, n0 = bx * 128;
    const int wm = (w >> 1) * 32, wn = (w & 1) * 64;

    f32x4 acc[2][4];
    #pragma unroll
    for (int mi = 0; mi < 2; ++mi)
        #pragma unroll
        for (int ni = 0; ni < 4; ++ni) acc[mi][ni] = (f32x4){0.f, 0.f, 0.f, 0.f};

    const int srow = lane >> 2;
    const int skc = (lane & 3) * 8;

    for (int k0 = 0; k0 < 1024; k0 += 32) {
        #pragma unroll
        for (int i = 0; i < 3; ++i) {
            const int seg = w * 3 + i;
            if (seg < 4) {
                const int row = seg * 16 + srow;
                glds16(&X[(size_t)(m0 + row) * 1024 + k0 + skc], &As[seg * 512]);
            } else {
                const int row = (seg - 4) * 16 + srow;
                glds16(&WT[(size_t)(n0 + row) * 1024 + k0 + skc], &Bs[(seg - 4) * 512]);
            }
        }
        __syncthreads();

        bf16x8 afr[2], bfr[4];
        #pragma unroll
        for (int mi = 0; mi < 2; ++mi)
            afr[mi] = *(const bf16x8*)&As[(wm + mi * 16 + l15) * 32 + quad * 8];
        #pragma unroll
        for (int ni = 0; ni < 4; ++ni)
            bfr[ni] = *(const bf16x8*)&Bs[(wn + ni * 16 + l15) * 32 + quad * 8];
        #pragma unroll
        for (int mi = 0; mi < 2; ++mi)
            #pragma unroll
            for (int ni = 0; ni < 4; ++ni)
                acc[mi][ni] = __builtin_amdgcn_mfma_f32_16x16x32_bf16(
                    afr[mi], bfr[ni], acc[mi][ni], 0, 0, 0);
        __syncthreads();
    }

    #pragma unroll
    for (int mi = 0; mi < 2; ++mi) {
        #pragma unroll
        for (int ni = 0; ni < 4; ++ni) {
            const int col = n0 + wn + ni * 16 + l15;
            const float bsv = bias[col];
            const int hh = col >> 6, d = col & 63;
            #pragma unroll
            for (int r = 0; r < 4; ++r) {
                const int row = m0 + wm + mi * 16 + quad * 4 + r;
                const int bb = row >> 11, s = row & 2047;
                const unsigned short v = (unsigned short)f2bf(acc[mi][ni][r] + bsv);
                if (z == 2) {
                    Ov[((((size_t)bb * Hv + hh) * 64 + d) << 11) + s] = v;   // V^T
                } else {
                    unsigned short* Od = (z == 0) ? Oq : Ok;
                    Od[((((size_t)bb * Hv + hh) * Sv + s) << 6) + d] = v;
                }
            }
        }
    }
}

// ---------------------------------------------------------------------------
// Output projection GEMM, 64Mx128N tile (grid 1024 = 4/CU vs 2/CU at 128²).
// A = attn-out bf16 in [B,H,S,64] layout via glds, B = wo^T, C fp32 [M,1024].
// ---------------------------------------------------------------------------
__global__ __launch_bounds__(256) void gemm_out(const unsigned short* __restrict__ Xp,
                                                const unsigned short* __restrict__ WT,
                                                const float* __restrict__ bias,
                                                float* __restrict__ C) {
    __shared__ short As[64 * 32];
    __shared__ short Bs[128 * 32];

    const int hw = blockIdx.x + 8 * blockIdx.y;       // nwg = 1024 (%8==0)
    const int wl = (hw & 7) * 128 + (hw >> 3);
    const int bx = wl & 7, by = wl >> 3;              // by in [0,128)

    const int t = threadIdx.x;
    const int lane = t & 63, w = t >> 6;
    const int l15 = lane & 15, quad = lane >> 4;
    const int m0 = by * 64, n0 = bx * 128;
    const int wm = (w >> 1) * 32, wn = (w & 1) * 64;

    f32x4 acc[2][4];
    #pragma unroll
    for (int mi = 0; mi < 2; ++mi)
        #pragma unroll
        for (int ni = 0; ni < 4; ++ni) acc[mi][ni] = (f32x4){0.f, 0.f, 0.f, 0.f};

    const int srow = lane >> 2;
    const int skc = (lane & 3) * 8;

    for (int k0 = 0; k0 < 1024; k0 += 32) {
        const int hh = k0 >> 6, db = (k0 & 63);
        #pragma unroll
        for (int i = 0; i < 3; ++i) {
            const int seg = w * 3 + i;
            if (seg < 4) {
                const int rb = m0 + seg * 16 + srow;
                const int bb = rb >> 11, s = rb & 2047;
                glds16(&Xp[((((size_t)bb * Hv + hh) * Sv + s) << 6) + db + skc], &As[seg * 512]);
            } else {
                const int row = (seg - 4) * 16 + srow;
                glds16(&WT[(size_t)(n0 + row) * 1024 + k0 + skc], &Bs[(seg - 4) * 512]);
            }
        }
        __syncthreads();

        bf16x8 afr[2], bfr[4];
        #pragma unroll
        for (int mi = 0; mi < 2; ++mi)
            afr[mi] = *(const bf16x8*)&As[(wm + mi * 16 + l15) * 32 + quad * 8];
        #pragma unroll
        for (int ni = 0; ni < 4; ++ni)
            bfr[ni] = *(const bf16x8*)&Bs[(wn + ni * 16 + l15) * 32 + quad * 8];
        #pragma unroll
        for (int mi = 0; mi < 2; ++mi)
            #pragma unroll
            for (int ni = 0; ni < 4; ++ni)
                acc[mi][ni] = __builtin_amdgcn_mfma_f32_16x16x32_bf16(
                    afr[mi], bfr[ni], acc[mi][ni], 0, 0, 0);
        __syncthreads();
    }

    #pragma unroll
    for (int mi = 0; mi < 2; ++mi) {
        #pragma unroll
        for (int ni = 0; ni < 4; ++ni) {
            const int col = n0 + wn + ni * 16 + l15;
            const float bsv = bias[col];
            #pragma unroll
            for (int r = 0; r < 4; ++r) {
                const int row = m0 + wm + mi * 16 + quad * 4 + r;
                C[(size_t)row * 1024 + col] = acc[mi][ni][r] + bsv;
            }
        }
    }
}

// ---------------------------------------------------------------------------
// Flash attention — EXACT R1 structure (empirical best: 107.9 us).
// OL=0: out [B,S,H*64] (fallback). OL=1: out [B,H,S,64] IN-PLACE into Q buf.
// ---------------------------------------------------------------------------
template <int OL>
__global__ __launch_bounds__(256, 4) void attn_mfma(const unsigned short* __restrict__ Q,
                                                    const unsigned short* __restrict__ Kg,
                                                    const unsigned short* __restrict__ VT,
                                                    const int* __restrict__ mask,
                                                    unsigned short* __restrict__ O) {
    __shared__ short Kl[64 * 72];    // [kk][d]
    __shared__ short Vl[64 * 72];    // [dv][kk]
    __shared__ short Sl[128 * 72];   // [qrow][kk]
    __shared__ float Mk[64];

    const int t = threadIdx.x;
    const int lane = t & 63, w = t >> 6;
    const int l15 = lane & 15, quad = lane >> 4;
    const int q0 = blockIdx.x * 128;
    const int h = blockIdx.y, b = blockIdx.z;
    const int bh = b * Hv + h;
    const size_t kvb = (size_t)bh * Sv * 64;
    const size_t vtb = (size_t)bh * 64 * Sv;

    bf16x8 qf[2][2];
    #pragma unroll
    for (int ni = 0; ni < 2; ++ni) {
        const size_t qa = kvb + (size_t)(q0 + w * 32 + ni * 16 + l15) * 64 + quad * 8;
        qf[ni][0] = *(const bf16x8*)&Q[qa];
        qf[ni][1] = *(const bf16x8*)&Q[qa + 32];
    }

    float l_acc[2] = {0.f, 0.f};
    f32x4 oacc[2][4];
    #pragma unroll
    for (int mi = 0; mi < 2; ++mi)
        #pragma unroll
        for (int ni = 0; ni < 4; ++ni) oacc[mi][ni] = (f32x4){0.f, 0.f, 0.f, 0.f};

    const int srow = t >> 2, sch = (t & 3) * 16;
    const unsigned short* Kst = Kg + kvb + (size_t)srow * 64 + sch;
    const unsigned short* Vst = VT + vtb + (size_t)srow * Sv + sch;
    const int* Mst = mask + (size_t)b * Sv;

    bf16x8 kr0 = *(const bf16x8*)&Kst[0];
    bf16x8 kr1 = *(const bf16x8*)&Kst[8];
    bf16x8 vr0 = *(const bf16x8*)&Vst[0];
    bf16x8 vr1 = *(const bf16x8*)&Vst[8];
    int mreg = (t < 64) ? Mst[t] : 0;

    constexpr float CS = 0.18033688011112042f;   // 0.125 * log2(e)
    constexpr float CM = NEGV * 1.4426950408889634f;

    for (int k0 = 0; k0 < Sv; k0 += 64) {
        __syncthreads();
        *(bf16x8*)&Kl[srow * 72 + sch] = kr0;
        *(bf16x8*)&Kl[srow * 72 + sch + 8] = kr1;
        *(bf16x8*)&Vl[srow * 72 + sch] = vr0;
        *(bf16x8*)&Vl[srow * 72 + sch + 8] = vr1;
        if (t < 64) Mk[t] = CM * (float)mreg;
        __syncthreads();

        if (k0 + 64 < Sv) {
            kr0 = *(const bf16x8*)&Kst[(size_t)(k0 + 64) * 64];
            kr1 = *(const bf16x8*)&Kst[(size_t)(k0 + 64) * 64 + 8];
            vr0 = *(const bf16x8*)&Vst[k0 + 64];
            vr1 = *(const bf16x8*)&Vst[k0 + 64 + 8];
            if (t < 64) mreg = Mst[k0 + 64 + t];
        }

        #pragma unroll
        for (int mi = 0; mi < 4; ++mi) {
            const bf16x8 kf0 = *(const bf16x8*)&Kl[(mi * 16 + l15) * 72 + quad * 8];
            const bf16x8 kf1 = *(const bf16x8*)&Kl[(mi * 16 + l15) * 72 + 32 + quad * 8];
            const float4 mk4 = *(const float4*)&Mk[mi * 16 + quad * 4];
            #pragma unroll
            for (int ni = 0; ni < 2; ++ni) {
                f32x4 st = (f32x4){0.f, 0.f, 0.f, 0.f};
                st = __builtin_amdgcn_mfma_f32_16x16x32_bf16(kf0, qf[ni][0], st, 0, 0, 0);
                st = __builtin_amdgcn_mfma_f32_16x16x32_bf16(kf1, qf[ni][1], st, 0, 0, 0);
                const float p0 = EXP2F(__builtin_fmaf(st[0], CS, mk4.x));
                const float p1 = EXP2F(__builtin_fmaf(st[1], CS, mk4.y));
                const float p2 = EXP2F(__builtin_fmaf(st[2], CS, mk4.z));
                const float p3 = EXP2F(__builtin_fmaf(st[3], CS, mk4.w));
                l_acc[ni] += (p0 + p1) + (p2 + p3);
                s16x4 pv = {f2bf(p0), f2bf(p1), f2bf(p2), f2bf(p3)};
                *(s16x4*)&Sl[(w * 32 + ni * 16 + l15) * 72 + mi * 16 + quad * 4] = pv;
            }
        }

        bf16x8 vf[4][2];
        #pragma unroll
        for (int ni = 0; ni < 4; ++ni) {
            vf[ni][0] = *(const bf16x8*)&Vl[(ni * 16 + l15) * 72 + quad * 8];
            vf[ni][1] = *(const bf16x8*)&Vl[(ni * 16 + l15) * 72 + 32 + quad * 8];
        }

        #pragma unroll
        for (int mi = 0; mi < 2; ++mi) {
            const bf16x8 pf0 = *(const bf16x8*)&Sl[(w * 32 + mi * 16 + l15) * 72 + quad * 8];
            const bf16x8 pf1 = *(const bf16x8*)&Sl[(w * 32 + mi * 16 + l15) * 72 + 32 + quad * 8];
            #pragma unroll
            for (int ni = 0; ni < 4; ++ni) {
                oacc[mi][ni] = __builtin_amdgcn_mfma_f32_16x16x32_bf16(pf0, vf[ni][0], oacc[mi][ni], 0, 0, 0);
                oacc[mi][ni] = __builtin_amdgcn_mfma_f32_16x16x32_bf16(pf1, vf[ni][1], oacc[mi][ni], 0, 0, 0);
            }
        }
    }

    #pragma unroll
    for (int mi = 0; mi < 2; ++mi) {
        float l = l_acc[mi];
        l += __shfl_xor(l, 16);
        l += __shfl_xor(l, 32);
        #pragma unroll
        for (int r = 0; r < 4; ++r) {
            const float lr = __shfl(l, quad * 4 + r, 64);
            const float inv = 1.0f / lr;
            const int s = q0 + w * 32 + mi * 16 + quad * 4 + r;
            #pragma unroll
            for (int ni = 0; ni < 4; ++ni) {
                const unsigned short v = (unsigned short)f2bf(oacc[mi][ni][r] * inv);
                if constexpr (OL == 0) {
                    O[((size_t)b * Sv + s) * (Hv * HD) + h * HD + ni * 16 + l15] = v;
                } else {
                    O[kvb + ((size_t)s << 6) + ni * 16 + l15] = v;
                }
            }
        }
    }
}

// ---------------------------------------------------------------------------
extern "C" void kernel_launch(void* const* d_in, const int* in_sizes, int n_in,
                              void* d_out, int out_size, void* d_ws, size_t ws_size,
                              hipStream_t stream) {
    const float* query = (const float*)d_in[0];
    const float* key   = (const float*)d_in[1];
    const float* value = (const float*)d_in[2];
    const int*   amask = (const int*)d_in[3];
    const float* wq = (const float*)d_in[4];
    const float* bq = (const float*)d_in[5];
    const float* wk = (const float*)d_in[6];
    const float* bk = (const float*)d_in[7];
    const float* wv = (const float*)d_in[8];
    const float* bv = (const float*)d_in[9];
    const float* wo = (const float*)d_in[10];
    const float* bo = (const float*)d_in[11];
    float* out = (float*)d_out;

    unsigned short* wsp = (unsigned short*)d_ws;
    dim3 bb(256);
    const size_t PBQ = (size_t)Bv * Hv * Sv * HD;  // 8,388,608 bf16 = 16 MB

    if (ws_size >= (size_t)112 * 1024 * 1024) {
        // ws: qb | kb | vb | ab | xb0 | xb1 | xb2  (7 x 16 MB)
        unsigned short* qb = wsp;
        unsigned short* kb = qb + PBQ;
        unsigned short* vb = kb + PBQ;
        unsigned short* ab = vb + PBQ;
        unsigned short* xb0 = ab + PBQ;
        unsigned short* xb1 = xb0 + PBQ;
        unsigned short* xb2 = xb1 + PBQ;

        transpose_w4<<<dim3(16, 16, 4), bb, 0, stream>>>(wq, wk, wv, wo, ab);
        cvt3<<<dim3(4096, 3), bb, 0, stream>>>(query, key, value, xb0, xb1, xb2);
        gemm_qkv_b<<<dim3(8, 128, 3), bb, 0, stream>>>(xb0, xb1, xb2, ab,
                                                       bq, bk, bv, qb, kb, vb, 0, 1, 2);
        attn_mfma<1><<<dim3(Sv / 128, Hv, Bv), bb, 0, stream>>>(qb, kb, vb, amask, qb);
        gemm_out<<<dim3(8, 128), bb, 0, stream>>>(qb, ab + (size_t)3 * 1048576, bo, out);
    } else if (ws_size >= (size_t)64 * 1024 * 1024) {
        // ws: qb | kb | vb | ab. bf16 activation scratch lives in dead d_out
        // (32 MB = 2 slots); K's activation staged after QV GEMM frees slot 0.
        unsigned short* qb = wsp;
        unsigned short* kb = qb + PBQ;
        unsigned short* vb = kb + PBQ;
        unsigned short* ab = vb + PBQ;
        unsigned short* dout_s = (unsigned short*)d_out;
        unsigned short* xv = dout_s;            // slot 0
        unsigned short* xq = dout_s + PBQ;      // slot 1
        unsigned short* xk = dout_s;            // slot 0 (reused)

        transpose_w4<<<dim3(16, 16, 4), bb, 0, stream>>>(wq, wk, wv, wo, ab);
        cvt3<<<dim3(4096, 2), bb, 0, stream>>>(value, query, query, xv, xq, xq);
        gemm_qkv_b<<<dim3(8, 128, 2), bb, 0, stream>>>(xq, xq, xv, ab,
                                                       bq, bk, bv, qb, kb, vb, 2, 0, 0);
        cvt3<<<dim3(4096, 1), bb, 0, stream>>>(key, key, key, xk, xk, xk);
        gemm_qkv_b<<<dim3(8, 128, 1), bb, 0, stream>>>(xk, xk, xk, ab,
                                                       bq, bk, bv, qb, kb, vb, 1, 1, 1);
        attn_mfma<1><<<dim3(Sv / 128, Hv, Bv), bb, 0, stream>>>(qb, kb, vb, amask, qb);
        gemm_out<<<dim3(8, 128), bb, 0, stream>>>(qb, ab + (size_t)3 * 1048576, bo, out);
    } else {
        // Per-batch fallback (verified path): qb|kb|vb|ab at 4 MB each.
        const size_t PQ = (size_t)Hv * Sv * HD;  // 2,097,152
        unsigned short* qb = wsp;
        unsigned short* kb = qb + PQ;
        unsigned short* vb = kb + PQ;
        unsigned short* ab = vb + PQ;
        const int M = Sv;
        dim3 gg(8, M / 128), gc(M * 1024 / 2048), gt(16, 16);
        for (int b = 0; b < Bv; ++b) {
            const size_t xoff = (size_t)b * Sv * Dv;
            unsigned short* wt_kb = kb;
            unsigned short* wt_out = (unsigned short*)(out + xoff);
            unsigned short* wt_vb = vb;

            cvt_bf16<<<gc, bb, 0, stream>>>(value + xoff, ab);
            transpose_w<<<gt, bb, 0, stream>>>(wv, wt_kb);
            gemm_mfma<1><<<gg, bb, 0, stream>>>(ab, wt_kb, bv, qb, M, 1024, 1024);
            transpose_v<<<dim3(Sv / 64, Hv), bb, 0, stream>>>(qb, vb);

            cvt_bf16<<<gc, bb, 0, stream>>>(query + xoff, ab);
            transpose_w<<<gt, bb, 0, stream>>>(wq, wt_kb);
            gemm_mfma<1><<<gg, bb, 0, stream>>>(ab, wt_kb, bq, qb, M, 1024, 1024);

            cvt_bf16<<<gc, bb, 0, stream>>>(key + xoff, ab);
            transpose_w<<<gt, bb, 0, stream>>>(wk, wt_out);
            gemm_mfma<1><<<gg, bb, 0, stream>>>(ab, wt_out, bk, kb, M, 1024, 1024);

            attn_mfma<0><<<dim3(Sv / 128, Hv, 1), bb, 0, stream>>>(qb, kb, vb,
                                                                   amask + (size_t)b * Sv, ab);

            transpose_w<<<gt, bb, 0, stream>>>(wo, wt_vb);
            gemm_mfma<0><<<gg, bb, 0, stream>>>(ab, wt_vb, bo, out + xoff, M, 1024, 1024);
        }
    }
}